// Round 7
// baseline (422.903 us; speedup 1.0000x reference)
//
#include <hip/hip_runtime.h>
#include <hip/hip_bf16.h>
#include <stdint.h>

typedef unsigned short u16;
typedef __attribute__((ext_vector_type(8))) short short8;
typedef __attribute__((ext_vector_type(4))) float floatx4;

#define NFEAT 256

__device__ __forceinline__ unsigned short f2b(float f) {
    unsigned int x = __builtin_bit_cast(unsigned int, f);
    x += 0x7fffu + ((x >> 16) & 1u);   // round-to-nearest-even
    return (unsigned short)(x >> 16);
}
__device__ __forceinline__ float sigmoidf_(float x) {
    return 1.0f / (1.0f + __expf(-x));
}

// -------- Kernel 0: prep --------
// grid 1024 x 256. Per block:
//  - wave w computes gbase[g]=relu(gf[g])·Wl[0:256]+bl and the bf16 gf copy, g=blk*4+w
//  - weight fp32->bf16 conversion (2 elems/thread)
//  - zero sacc (float4/thread) and lacc
__global__ void __launch_bounds__(256)
k0_prep(const float* __restrict__ gf, const float* __restrict__ Wl,
        const float* __restrict__ bl,
        const float* __restrict__ Wp, const float* __restrict__ Wih,
        const float* __restrict__ Whh,
        u16* __restrict__ gfb, float* __restrict__ gbase,
        u16* __restrict__ wpb, u16* __restrict__ wihb, u16* __restrict__ whhb,
        float* __restrict__ sacc, float* __restrict__ lacc, int G)
{
    const int blk = blockIdx.x;
    const int t = threadIdx.x;
    const int lane = t & 63;
    const int w = t >> 6;
    const int gid = blk * 256 + t;

    // ---- weight conversion (pairs; region boundaries are even) ----
    {
        const int n1 = 256 * 256;            // Wp
        const int n2 = n1 + 768 * 256;       // + W_ih
        const int n3 = n2 + 768 * 256;       // + W_hh
        int idx = gid * 2;
        if (idx < n3) {
            const float* src; u16* dst; int o;
            if (idx < n1)      { src = Wp;  dst = wpb;  o = idx; }
            else if (idx < n2) { src = Wih; dst = wihb; o = idx - n1; }
            else               { src = Whh; dst = whhb; o = idx - n2; }
            float2 v = *(const float2*)(src + o);
            dst[o]     = f2b(v.x);
            dst[o + 1] = f2b(v.y);
        }
    }

    // ---- gbase + gfb for graph g = blk*4 + w ----
    {
        const int g = blk * 4 + w;
        if (g < G) {
            float4 gv = *(const float4*)(gf + (size_t)g * NFEAT + lane * 4);
            ushort4 b4 = { f2b(gv.x), f2b(gv.y), f2b(gv.z), f2b(gv.w) };
            *(ushort4*)(gfb + (size_t)g * NFEAT + lane * 4) = b4;
            float4 wv = *(const float4*)(Wl + lane * 4);
            float v = fmaxf(gv.x, 0.f) * wv.x + fmaxf(gv.y, 0.f) * wv.y
                    + fmaxf(gv.z, 0.f) * wv.z + fmaxf(gv.w, 0.f) * wv.w;
            #pragma unroll
            for (int o = 32; o > 0; o >>= 1) v += __shfl_xor(v, o);
            if (lane == 0) gbase[g] = v + bl[0];
        }
    }

    // ---- zero accumulators ----
    {
        float4 z4 = {0.f, 0.f, 0.f, 0.f};
        size_t idx4 = (size_t)gid * 4;
        if (idx4 < (size_t)G * NFEAT) *(float4*)(sacc + idx4) = z4;
        if (gid < G) lacc[gid] = 0.0f;
    }
}

// -------- Kernel 1: node-span streaming attention pooling --------
// Block = 512 contiguous nodes; wave = 128 contiguous rows, 4 rows/iter with
// depth-4 prefetch. p = exp(leaky(z)) without max subtraction (logits are
// 0.05-scale dots, |z| < ~10). Wave-private (acc,l) flushed to fp32 global
// accumulators via device-scope atomicAdd at segment boundaries.
__global__ void __launch_bounds__(256)
k1_attn_pool(const float* __restrict__ nf, const int* __restrict__ seg,
             const float* __restrict__ Wl, const float* __restrict__ gbase,
             float* __restrict__ sacc, float* __restrict__ lacc, int V)
{
    const int t = threadIdx.x;
    const int lane = t & 63;
    const int w = t >> 6;
    const int s0 = blockIdx.x * 512 + w * 128;
    const int end = s0 + 128;

    const float4 wn = *(const float4*)(Wl + NFEAT + lane * 4);
    const float* base = nf + (size_t)s0 * NFEAT + lane * 4;

    float4 x[4];
    #pragma unroll
    for (int r = 0; r < 4; ++r) x[r] = *(const float4*)(base + (size_t)r * NFEAT);

    int gcur = seg[s0];
    float gb = gbase[gcur];
    float4 acc = {0.f, 0.f, 0.f, 0.f};
    float l = 0.0f;

    for (int i = s0; i < end; i += 4) {
        float4 nx[4] = {{0,0,0,0},{0,0,0,0},{0,0,0,0},{0,0,0,0}};
        if (i + 4 < end) {
            #pragma unroll
            for (int r = 0; r < 4; ++r)
                nx[r] = *(const float4*)(base + (size_t)(i + 4 + r - s0) * NFEAT);
        }
        const int4 sg = *(const int4*)(seg + i);

        float d[4];
        #pragma unroll
        for (int r = 0; r < 4; ++r)
            d[r] = x[r].x * wn.x + x[r].y * wn.y + x[r].z * wn.z + x[r].w * wn.w;
        #pragma unroll
        for (int o = 32; o > 0; o >>= 1) {
            #pragma unroll
            for (int r = 0; r < 4; ++r) d[r] += __shfl_xor(d[r], o);
        }

        const int sgr[4] = { sg.x, sg.y, sg.z, sg.w };
        #pragma unroll
        for (int r = 0; r < 4; ++r) {
            if (sgr[r] != gcur) {               // wave-uniform branch
                if (l > 0.0f) {
                    float* dst = sacc + (size_t)gcur * NFEAT + lane * 4;
                    atomicAdd(dst + 0, acc.x);
                    atomicAdd(dst + 1, acc.y);
                    atomicAdd(dst + 2, acc.z);
                    atomicAdd(dst + 3, acc.w);
                    if (lane == 0) atomicAdd(lacc + gcur, l);
                }
                gcur = sgr[r];
                gb = gbase[gcur];
                acc.x = acc.y = acc.z = acc.w = 0.f;
                l = 0.f;
            }
            float z = d[r] + gb;
            z = (z > 0.0f) ? z : 0.01f * z;     // leaky_relu 0.01
            float p = __expf(z);
            l += p;
            acc.x += p * x[r].x;
            acc.y += p * x[r].y;
            acc.z += p * x[r].z;
            acc.w += p * x[r].w;
        }
        x[0] = nx[0]; x[1] = nx[1]; x[2] = nx[2]; x[3] = nx[3];
    }
    if (l > 0.0f) {
        float* dst = sacc + (size_t)gcur * NFEAT + lane * 4;
        atomicAdd(dst + 0, acc.x);
        atomicAdd(dst + 1, acc.y);
        atomicAdd(dst + 2, acc.z);
        atomicAdd(dst + 3, acc.w);
        if (lane == 0) atomicAdd(lacc + gcur, l);
    }
}

// -------- Kernel 2 (fused): normalize + project + elu + GRU cell --------
// One block per 16-graph stripe (512 thr = 8 waves). Phase A: s = sacc/lacc
// (fp32->bf16 in-register), ctx = elu(s@Wp^T + bp*pres) into LDS. Phase B:
// GRU GEMMs; gates fused; fp32 output.
#define CTX_LD 264   // 16-row LDS ctx, row stride 264 u16 (528 B) to break banks
__global__ void __launch_bounds__(512)
k2_fused(const float* __restrict__ sacc, const float* __restrict__ lacc,
         const u16* __restrict__ wpb,
         const float* __restrict__ bp,
         const u16* __restrict__ gfb, const float* __restrict__ gf,
         const u16* __restrict__ wihb, const u16* __restrict__ whhb,
         const float* __restrict__ bih, const float* __restrict__ bhh,
         float* __restrict__ out)
{
    __shared__ u16 ctx[16][CTX_LD];
    const int t = threadIdx.x;
    const int w = t >> 6;            // wave 0..7
    const int lane = t & 63;
    const int m0 = blockIdx.x * 16;  // graph-row stripe
    const int lr = lane & 15;
    const int kh = lane >> 4;

    // ---- phase A: wave w computes ctx col-tiles {2w, 2w+1} ----
    {
        const float* A = sacc + (size_t)(m0 + lr) * NFEAT + kh * 8;
        const float lrow = lacc[m0 + lr];
        const float inv = (lrow > 0.0f) ? 1.0f / lrow : 0.0f;
        short8 af[8];
        #pragma unroll
        for (int kk = 0; kk < 8; ++kk) {
            float4 a0 = *(const float4*)(A + kk * 32);
            float4 a1 = *(const float4*)(A + kk * 32 + 4);
            short8 v;
            v[0] = (short)f2b(a0.x * inv); v[1] = (short)f2b(a0.y * inv);
            v[2] = (short)f2b(a0.z * inv); v[3] = (short)f2b(a0.w * inv);
            v[4] = (short)f2b(a1.x * inv); v[5] = (short)f2b(a1.y * inv);
            v[6] = (short)f2b(a1.z * inv); v[7] = (short)f2b(a1.w * inv);
            af[kk] = v;
        }

        #pragma unroll
        for (int nt = 0; nt < 2; ++nt) {
            const int n0 = (w * 2 + nt) * 16;
            const short* B = (const short*)wpb + (size_t)(n0 + lr) * NFEAT + kh * 8;
            floatx4 acc = {0.f, 0.f, 0.f, 0.f};
            #pragma unroll
            for (int kk = 0; kk < 8; ++kk)
                acc = __builtin_amdgcn_mfma_f32_16x16x32_bf16(af[kk], *(const short8*)(B + kk * 32), acc, 0, 0, 0);
            const int col = n0 + lr;
            const float bias = bp[col];
            #pragma unroll
            for (int r = 0; r < 4; ++r) {
                int rl = kh * 4 + r;                    // local row (C/D mapping)
                float presv = (lacc[m0 + rl] > 0.0f) ? 1.0f : 0.0f;
                float x = acc[r] + bias * presv;
                x = (x > 0.0f) ? x : (__expf(x) - 1.0f);  // elu
                ctx[rl][col] = f2b(x);
            }
        }
    }
    __syncthreads();

    // ---- phase B: wave w handles out col-tiles {2w, 2w+1} ----
    short8 a1[8], a2[8];
    #pragma unroll
    for (int kk = 0; kk < 8; ++kk)
        a1[kk] = *(const short8*)&ctx[lr][kk * 32 + kh * 8];
    {
        const short* A2 = (const short*)gfb + (size_t)(m0 + lr) * NFEAT + kh * 8;
        #pragma unroll
        for (int kk = 0; kk < 8; ++kk) a2[kk] = *(const short8*)(A2 + kk * 32);
    }

    #pragma unroll
    for (int jt = 0; jt < 2; ++jt) {
        const int j0 = (w * 2 + jt) * 16;
        const size_t boff = (size_t)(j0 + lr) * NFEAT + kh * 8;
        const short* Bir = (const short*)wihb + boff;
        const short* Biz = Bir + 256 * NFEAT;
        const short* Bin = Bir + 512 * NFEAT;
        const short* Bhr = (const short*)whhb + boff;
        const short* Bhz = Bhr + 256 * NFEAT;
        const short* Bhn = Bhr + 512 * NFEAT;

        floatx4 air = {0,0,0,0}, aiz = {0,0,0,0}, ain = {0,0,0,0};
        floatx4 ahr = {0,0,0,0}, ahz = {0,0,0,0}, ahn = {0,0,0,0};
        #pragma unroll
        for (int kk = 0; kk < 8; ++kk) {
            const int k = kk * 32;
            air = __builtin_amdgcn_mfma_f32_16x16x32_bf16(a1[kk], *(const short8*)(Bir + k), air, 0, 0, 0);
            aiz = __builtin_amdgcn_mfma_f32_16x16x32_bf16(a1[kk], *(const short8*)(Biz + k), aiz, 0, 0, 0);
            ain = __builtin_amdgcn_mfma_f32_16x16x32_bf16(a1[kk], *(const short8*)(Bin + k), ain, 0, 0, 0);
            ahr = __builtin_amdgcn_mfma_f32_16x16x32_bf16(a2[kk], *(const short8*)(Bhr + k), ahr, 0, 0, 0);
            ahz = __builtin_amdgcn_mfma_f32_16x16x32_bf16(a2[kk], *(const short8*)(Bhz + k), ahz, 0, 0, 0);
            ahn = __builtin_amdgcn_mfma_f32_16x16x32_bf16(a2[kk], *(const short8*)(Bhn + k), ahn, 0, 0, 0);
        }
        const int col = j0 + lr;
        const float b_ir = bih[col], b_iz = bih[256 + col], b_in = bih[512 + col];
        const float b_hr = bhh[col], b_hz = bhh[256 + col], b_hn = bhh[512 + col];
        #pragma unroll
        for (int r = 0; r < 4; ++r) {
            int row = m0 + kh * 4 + r;
            float rg = sigmoidf_((air[r] + b_ir) + (ahr[r] + b_hr));
            float ug = sigmoidf_((aiz[r] + b_iz) + (ahz[r] + b_hz));
            float ng = tanhf((ain[r] + b_in) + rg * (ahn[r] + b_hn));
            float h  = gf[(size_t)row * NFEAT + col];   // fp32 hidden state
            out[(size_t)row * NFEAT + col] = (1.0f - ug) * ng + ug * h;
        }
    }
}

extern "C" void kernel_launch(void* const* d_in, const int* in_sizes, int n_in,
                              void* d_out, int out_size, void* d_ws, size_t ws_size,
                              hipStream_t stream)
{
    const float* nf  = (const float*)d_in[0];   // node_feats [V,256] fp32
    const float* gf  = (const float*)d_in[1];   // g_feats   [G,256] fp32
    const int*   seg = (const int*)d_in[2];     // segment_ids [V], sorted
    const float* Wl  = (const float*)d_in[3];   // [1,512]
    const float* bl  = (const float*)d_in[4];   // [1]
    const float* Wp  = (const float*)d_in[5];   // [256,256]
    const float* bp  = (const float*)d_in[6];   // [256]
    const float* Wih = (const float*)d_in[7];   // [768,256]
    const float* Whh = (const float*)d_in[8];   // [768,256]
    const float* bih = (const float*)d_in[9];   // [768]
    const float* bhh = (const float*)d_in[10];  // [768]

    const int V = in_sizes[2];
    const int G = in_sizes[1] / NFEAT;

    // workspace layout (16B-aligned regions)
    char* ws = (char*)d_ws;
    float* sacc = (float*)ws;                         ws += (size_t)G * NFEAT * 4;  // 4 MB
    float* lacc = (float*)ws;                         ws += (size_t)G * 4;          // 16 KB
    float* gbase= (float*)ws;                         ws += (size_t)G * 4;          // 16 KB
    u16*   gfb  = (u16*)ws;                           ws += (size_t)G * NFEAT * 2;  // 2 MB
    u16*   wpb  = (u16*)ws;                           ws += (size_t)256 * 256 * 2;  // 128 KB
    u16*   wihb = (u16*)ws;                           ws += (size_t)768 * 256 * 2;  // 384 KB
    u16*   whhb = (u16*)ws;                           ws += (size_t)768 * 256 * 2;  // 384 KB

    const int k0_blocks = (G * NFEAT / 4 + 255) / 256;   // covers zeroing, gbase, weights
    k0_prep<<<k0_blocks, 256, 0, stream>>>(gf, Wl, bl, Wp, Wih, Whh,
                                           gfb, gbase, wpb, wihb, whhb,
                                           sacc, lacc, G);
    k1_attn_pool<<<V / 512, 256, 0, stream>>>(nf, seg, Wl, gbase, sacc, lacc, V);
    k2_fused<<<G / 16, 512, 0, stream>>>(sacc, lacc, wpb, bp, gfb, gf,
                                         wihb, whhb, bih, bhh, (float*)d_out);
    (void)ws_size; (void)n_in; (void)out_size;
}